// Round 15
// baseline (1169.399 us; speedup 1.0000x reference)
//
#include <hip/hip_runtime.h>
#include <hip/hip_bf16.h>
#include <cstdint>
#include <cstddef>

#define NTOK 16384
#define DIM 1024
#define NEXP 8
#define HDIM 4096
#define BM 256
#define BN 256
#define BK 64
#define MAXTILES 160
#define GRIDX_COMB 160
#define GRIDX_FALL 80
#define GEMM_SMEM 131072

typedef unsigned short u16;
typedef short bf16x8 __attribute__((ext_vector_type(8)));
typedef float f32x4 __attribute__((ext_vector_type(4)));

typedef const __attribute__((address_space(1))) void* gas_ptr;
typedef __attribute__((address_space(3))) void* las_ptr;

__device__ __forceinline__ void gload16(const void* g, void* l) {
  __builtin_amdgcn_global_load_lds((gas_ptr)g, (las_ptr)l, 16, 0, 0);
}

__device__ __forceinline__ u16 f2b(float f) {
  union { float f; unsigned u; } v;
  v.f = f;
  unsigned r = v.u + 0x7fffu + ((v.u >> 16) & 1u);
  return (u16)(r >> 16);
}

// tanh-form GELU via hw exp/rcp: ~9 branch-free inst, |err| <= ~3e-4 vs exact
__device__ __forceinline__ float gelu_fast(float x) {
  float x2 = x * x;
  float u = x * fmaf(0.044715f, x2, 1.0f);
  float m = fminf(1.5957691216f * u, 55.0f);
  float e = __expf(m);
  float r = __builtin_amdgcn_rcpf(e + 1.0f);
  return x * e * r;
}

// bijective XCD-chunked swizzle (m204), y-panel fastest within a chunk:
// consecutive same-XCD blocks cover all N-panels of ONE row-tile -> A-tile L2 reuse
__device__ __forceinline__ int2 swz_block_yf() {
  int GX = gridDim.x, GY = gridDim.y;
  int nwg = GX * GY;
  int bid = (int)blockIdx.y * GX + (int)blockIdx.x;
  int q = nwg >> 3, r = nwg & 7;
  int xcd = bid & 7, idx = bid >> 3;
  int wg = (xcd < r) ? (xcd * (q + 1) + idx)
                     : (r * (q + 1) + (xcd - r) * q + idx);
  return make_int2(wg / GY, wg % GY);   // (tile index, N-panel)
}

// ---- gating: logits (f64 accum), top-2, softmax weights; also emits xb=bf16(x) ----
__global__ __launch_bounds__(256) void gating_kernel(
    const float* __restrict__ x, const float* __restrict__ Wg,
    const float* __restrict__ bg, int* __restrict__ e01,
    float2* __restrict__ w01, int* __restrict__ counts, u16* __restrict__ xb)
{
  __shared__ float4 wgl[NEXP][256];
  __shared__ int lcnt[16];
  int t = threadIdx.x;
  if (t < 16) lcnt[t] = 0;
  float* wglf = (float*)wgl;
  const float4* wg4 = (const float4*)Wg;
  for (int i = t; i < 2048; i += 256) {
    float4 v = wg4[i];
    int d = i >> 1, eb = (i & 1) * 4;
    wglf[(eb + 0) * 1024 + d] = v.x;
    wglf[(eb + 1) * 1024 + d] = v.y;
    wglf[(eb + 2) * 1024 + d] = v.z;
    wglf[(eb + 3) * 1024 + d] = v.w;
  }
  __syncthreads();
  int lane = t & 63, wid = t >> 6;
  int tok0 = blockIdx.x * 16 + wid * 4;
  for (int s = 0; s < 4; ++s) {
    int n = tok0 + s;
    const float4* xr = (const float4*)(x + (size_t)n * DIM);
    float4 xv[4];
    #pragma unroll
    for (int k = 0; k < 4; ++k) xv[k] = xr[lane + k * 64];
    ushort4* xo = (ushort4*)(xb + (size_t)n * DIM);
    #pragma unroll
    for (int k = 0; k < 4; ++k) {
      ushort4 o;
      o.x = f2b(xv[k].x); o.y = f2b(xv[k].y); o.z = f2b(xv[k].z); o.w = f2b(xv[k].w);
      xo[lane + k * 64] = o;
    }
    double acc[NEXP];
    #pragma unroll
    for (int e = 0; e < NEXP; ++e) acc[e] = 0.0;
    #pragma unroll
    for (int k = 0; k < 4; ++k) {
      #pragma unroll
      for (int e = 0; e < NEXP; ++e) {
        float4 w = wgl[e][lane + k * 64];
        acc[e] += (double)(xv[k].x * w.x) + (double)(xv[k].y * w.y)
                + (double)(xv[k].z * w.z) + (double)(xv[k].w * w.w);
      }
    }
    #pragma unroll
    for (int e = 0; e < NEXP; ++e) {
      for (int off = 32; off; off >>= 1) acc[e] += __shfl_down(acc[e], off, 64);
    }
    if (lane == 0) {
      float v[NEXP];
      #pragma unroll
      for (int e = 0; e < NEXP; ++e) v[e] = (float)acc[e] + bg[e];
      int e0 = 0; float v0 = v[0];
      #pragma unroll
      for (int e = 1; e < NEXP; ++e) if (v[e] > v0) { v0 = v[e]; e0 = e; }
      int e1 = -1; float v1 = -1e30f;
      #pragma unroll
      for (int e = 0; e < NEXP; ++e) if (e != e0 && v[e] > v1) { v1 = v[e]; e1 = e; }
      float d = expf(v1 - v0);
      float w0 = 1.0f / (1.0f + d);
      float w1 = d * w0;
      e01[n] = e0 | (e1 << 8);
      w01[n] = make_float2(w0, w1);
      atomicAdd(&lcnt[e0], 1);
      atomicAdd(&lcnt[8 + e1], 1);
    }
  }
  __syncthreads();
  if (t < 16 && lcnt[t]) atomicAdd(&counts[t], lcnt[t]);
}

// ---------------- plan: offsets + tile directory ----------------
__global__ void plan_kernel(const int* __restrict__ counts, int* __restrict__ offsets,
                            int* __restrict__ cursors, int* __restrict__ numTiles,
                            int4* __restrict__ tiledir, int combined)
{
  if (threadIdx.x == 0 && blockIdx.x == 0) {
    for (int p = 0; p < 2; ++p) {
      int o = 0;
      for (int e = 0; e < NEXP; ++e) {
        offsets[p * 8 + e] = o;
        cursors[p * 8 + e] = o;
        o += counts[p * 8 + e];
      }
    }
    if (combined) {
      int idx = 0;
      for (int s = 0; s < 16; ++s) {
        int p = s >> 3, e = s & 7;
        int c = counts[s];
        int base = p * NTOK + offsets[s];
        for (int st = 0; st < c; st += BM) {
          tiledir[idx] = make_int4(e, base + st, (c - st) < BM ? (c - st) : BM, 0);
          ++idx;
        }
      }
      numTiles[0] = idx;
      numTiles[1] = 0;
    } else {
      for (int p = 0; p < 2; ++p) {
        int idx = 0;
        for (int e = 0; e < NEXP; ++e) {
          int c = counts[p * 8 + e];
          int base = p * NTOK + offsets[p * 8 + e];
          for (int st = 0; st < c; st += BM) {
            tiledir[p * MAXTILES + idx] = make_int4(e, base + st, (c - st) < BM ? (c - st) : BM, 0);
            ++idx;
          }
        }
        numTiles[p] = idx;
      }
    }
  }
}

// ---------------- scatter tokens into per-expert lists ----------------
__global__ __launch_bounds__(256) void scatter_kernel(
    const int* __restrict__ e01, const float2* __restrict__ w01,
    int* __restrict__ cursors, int* __restrict__ rowlist, float* __restrict__ roww)
{
  int n = blockIdx.x * 256 + threadIdx.x;
  int ee = e01[n];
  float2 w = w01[n];
  int e0 = ee & 255, e1 = ee >> 8;
  int p0 = atomicAdd(&cursors[e0], 1);
  rowlist[p0] = n; roww[p0] = w.x;
  int p1 = atomicAdd(&cursors[8 + e1], 1);
  rowlist[NTOK + p1] = n; roww[NTOK + p1] = w.y;
}

// ---------------- fp32 [R][C] -> bf16 [C][R] transpose-convert, per expert ----------------
__global__ __launch_bounds__(256) void transpose_convert_kernel(
    const float* __restrict__ in, u16* __restrict__ out, int R, int C)
{
  __shared__ float tile[64][65];
  size_t base = (size_t)blockIdx.z * R * C;
  int r0 = blockIdx.x * 64, c0 = blockIdx.y * 64;
  int t = threadIdx.x;
  int lr = t >> 4, lc4 = (t & 15) * 4;
  #pragma unroll
  for (int i = 0; i < 4; ++i) {
    float4 v = *reinterpret_cast<const float4*>(
        &in[base + (size_t)(r0 + i * 16 + lr) * C + c0 + lc4]);
    tile[i * 16 + lr][lc4 + 0] = v.x;
    tile[i * 16 + lr][lc4 + 1] = v.y;
    tile[i * 16 + lr][lc4 + 2] = v.z;
    tile[i * 16 + lr][lc4 + 3] = v.w;
  }
  __syncthreads();
  #pragma unroll
  for (int i = 0; i < 4; ++i) {
    int oc = i * 16 + lr;
    ushort4 o;
    o.x = f2b(tile[lc4 + 0][oc]);
    o.y = f2b(tile[lc4 + 1][oc]);
    o.z = f2b(tile[lc4 + 2][oc]);
    o.w = f2b(tile[lc4 + 3][oc]);
    *reinterpret_cast<ushort4*>(&out[base + (size_t)(c0 + oc) * R + r0 + lc4]) = o;
  }
}

// ================= 256x256 double-buffered 2-phase grouped GEMMs (R9 bodies) =====
// 512 threads = 8 waves (2M x 4N); per-wave 128x64; BK=64; dbuf LDS 128KB; 1 blk/CU.
// Block order: y-fastest within XCD chunk (A-tile L2 reuse across the N-panels).

// GEMM1: h[row - hbase] = gelu_fast(gather(x) @ W1[e]' + b1[e])
__global__ __launch_bounds__(512, 2) void gemm1_kernel(
    const u16* __restrict__ xb, const u16* __restrict__ w1t,
    const float* __restrict__ b1, u16* __restrict__ h,
    const int* __restrict__ rowlist, const int4* __restrict__ tiledir,
    const int* __restrict__ numTiles, int hbase)
{
  extern __shared__ u16 smem[];
  u16* Aldsb = smem;              // [2][256*64]
  u16* Bldsb = smem + 32768;      // [2][256*64]
  __shared__ int tok[BM];
  int2 bxy = swz_block_yf();
  int bx = bxy.x, by = bxy.y;
  if (bx >= *numTiles) return;
  int4 td = tiledir[bx];
  int e = td.x, row0 = td.y, rows = td.z;
  int n0 = by * BN;
  int t = threadIdx.x, lane = t & 63, wid = t >> 6;
  for (int i = t; i < BM; i += 512) {
    int p = row0 + i; if (p > 2 * NTOK - 1) p = 2 * NTOK - 1;
    tok[i] = rowlist[p];
  }
  __syncthreads();
  int schunk = (lane & 7) ^ (lane >> 3);
  const u16* gA[4]; const u16* gB[4];
  #pragma unroll
  for (int i = 0; i < 4; ++i) {
    int row = (wid * 4 + i) * 8 + (lane >> 3);
    gA[i] = xb + (size_t)tok[row] * DIM + schunk * 8;
    gB[i] = w1t + ((size_t)e * HDIM + n0 + row) * DIM + schunk * 8;
  }
  f32x4 acc[8][4] = {};
  int wr = wid >> 2, wc = wid & 3;
  int arow = lane & 15, cbase = lane >> 4, csw = arow & 7;
  #pragma unroll
  for (int i = 0; i < 4; ++i) {
    gload16(gA[i], &Aldsb[(wid * 4 + i) * 512]);
    gload16(gB[i], &Bldsb[(wid * 4 + i) * 512]);
  }
  __syncthreads();
  const int NKT = DIM / BK;
  for (int kt = 0; kt < NKT; ++kt) {
    int buf = kt & 1;
    if (kt + 1 < NKT) {
      int bo = (buf ^ 1) * 16384;
      #pragma unroll
      for (int i = 0; i < 4; ++i) {
        gload16(gA[i] + (kt + 1) * BK, &Aldsb[bo + (wid * 4 + i) * 512]);
        gload16(gB[i] + (kt + 1) * BK, &Bldsb[bo + (wid * 4 + i) * 512]);
      }
    }
    const u16* Ab = Aldsb + buf * 16384;
    const u16* Bb = Bldsb + buf * 16384;
    #pragma unroll
    for (int kk = 0; kk < 2; ++kk) {
      int cp = ((kk * 4 + cbase) ^ csw) * 8;
      bf16x8 a[8], b[4];
      #pragma unroll
      for (int m = 0; m < 8; ++m)
        a[m] = *reinterpret_cast<const bf16x8*>(&Ab[(wr * 128 + m * 16 + arow) * BK + cp]);
      #pragma unroll
      for (int n = 0; n < 4; ++n)
        b[n] = *reinterpret_cast<const bf16x8*>(&Bb[(wc * 64 + n * 16 + arow) * BK + cp]);
      __builtin_amdgcn_s_setprio(1);
      #pragma unroll
      for (int m = 0; m < 8; ++m)
        #pragma unroll
        for (int n = 0; n < 4; ++n)
          acc[m][n] = __builtin_amdgcn_mfma_f32_16x16x32_bf16(a[m], b[n], acc[m][n], 0, 0, 0);
      __builtin_amdgcn_s_setprio(0);
    }
    __syncthreads();
  }
  int rsub = (lane >> 4) * 4;
  #pragma unroll
  for (int m = 0; m < 8; ++m) {
    int lrb = wr * 128 + m * 16 + rsub;
    #pragma unroll
    for (int n = 0; n < 4; ++n) {
      int col = n0 + wc * 64 + n * 16 + arow;
      float bv = b1[e * HDIM + col];
      #pragma unroll
      for (int r = 0; r < 4; ++r) {
        int lr = lrb + r;
        if (lr < rows) {
          float v = gelu_fast(acc[m][n][r] + bv);
          h[(size_t)(row0 + lr - hbase) * HDIM + col] = f2b(v);
        }
      }
    }
  }
}

// GEMM2: out[tok] += w * (h[row - hbase] @ W2[e]' + b2[e])   (atomicAdd, out pre-zeroed)
__global__ __launch_bounds__(512, 2) void gemm2_kernel(
    const u16* __restrict__ h, const u16* __restrict__ w2t,
    const float* __restrict__ b2, float* __restrict__ out,
    const int* __restrict__ rowlist, const float* __restrict__ roww,
    const int4* __restrict__ tiledir, const int* __restrict__ numTiles, int hbase)
{
  extern __shared__ u16 smem[];
  u16* Aldsb = smem;
  u16* Bldsb = smem + 32768;
  __shared__ int tok[BM];
  __shared__ float wt[BM];
  int2 bxy = swz_block_yf();
  int bx = bxy.x, by = bxy.y;
  if (bx >= *numTiles) return;
  int4 td = tiledir[bx];
  int e = td.x, row0 = td.y, rows = td.z;
  int n0 = by * BN;
  int t = threadIdx.x, lane = t & 63, wid = t >> 6;
  for (int i = t; i < BM; i += 512) {
    int p = row0 + i; if (p > 2 * NTOK - 1) p = 2 * NTOK - 1;
    tok[i] = rowlist[p];
    wt[i] = roww[p];
  }
  __syncthreads();   // cross-wave tok/wt visibility
  int schunk = (lane & 7) ^ (lane >> 3);
  const u16* gA[4]; const u16* gB[4];
  #pragma unroll
  for (int i = 0; i < 4; ++i) {
    int row = (wid * 4 + i) * 8 + (lane >> 3);
    int hr = row < rows ? row : (rows - 1);
    gA[i] = h + (size_t)(row0 + hr - hbase) * HDIM + schunk * 8;
    gB[i] = w2t + ((size_t)e * DIM + n0 + row) * HDIM + schunk * 8;
  }
  f32x4 acc[8][4] = {};
  int wr = wid >> 2, wc = wid & 3;
  int arow = lane & 15, cbase = lane >> 4, csw = arow & 7;
  #pragma unroll
  for (int i = 0; i < 4; ++i) {
    gload16(gA[i], &Aldsb[(wid * 4 + i) * 512]);
    gload16(gB[i], &Bldsb[(wid * 4 + i) * 512]);
  }
  __syncthreads();
  const int NKT = HDIM / BK;
  for (int kt = 0; kt < NKT; ++kt) {
    int buf = kt & 1;
    if (kt + 1 < NKT) {
      int bo = (buf ^ 1) * 16384;
      #pragma unroll
      for (int i = 0; i < 4; ++i) {
        gload16(gA[i] + (kt + 1) * BK, &Aldsb[bo + (wid * 4 + i) * 512]);
        gload16(gB[i] + (kt + 1) * BK, &Bldsb[bo + (wid * 4 + i) * 512]);
      }
    }
    const u16* Ab = Aldsb + buf * 16384;
    const u16* Bb = Bldsb + buf * 16384;
    #pragma unroll
    for (int kk = 0; kk < 2; ++kk) {
      int cp = ((kk * 4 + cbase) ^ csw) * 8;
      bf16x8 a[8], b[4];
      #pragma unroll
      for (int m = 0; m < 8; ++m)
        a[m] = *reinterpret_cast<const bf16x8*>(&Ab[(wr * 128 + m * 16 + arow) * BK + cp]);
      #pragma unroll
      for (int n = 0; n < 4; ++n)
        b[n] = *reinterpret_cast<const bf16x8*>(&Bb[(wc * 64 + n * 16 + arow) * BK + cp]);
      __builtin_amdgcn_s_setprio(1);
      #pragma unroll
      for (int m = 0; m < 8; ++m)
        #pragma unroll
        for (int n = 0; n < 4; ++n)
          acc[m][n] = __builtin_amdgcn_mfma_f32_16x16x32_bf16(a[m], b[n], acc[m][n], 0, 0, 0);
      __builtin_amdgcn_s_setprio(0);
    }
    __syncthreads();
  }
  int rsub = (lane >> 4) * 4;
  #pragma unroll
  for (int m = 0; m < 8; ++m) {
    int lrb = wr * 128 + m * 16 + rsub;
    #pragma unroll
    for (int n = 0; n < 4; ++n) {
      int col = n0 + wc * 64 + n * 16 + arow;
      float bv = b2[e * DIM + col];
      #pragma unroll
      for (int r = 0; r < 4; ++r) {
        int lr = lrb + r;
        if (lr < rows) {
          float v = (acc[m][n][r] + bv) * wt[lr];
          atomicAdd(&out[(size_t)tok[lr] * DIM + col], v);
        }
      }
    }
  }
}

// ---------------- launcher ----------------
extern "C" void kernel_launch(void* const* d_in, const int* in_sizes, int n_in,
                              void* d_out, int out_size, void* d_ws, size_t ws_size,
                              hipStream_t stream)
{
  const float* x  = (const float*)d_in[0];
  const float* Wg = (const float*)d_in[1];
  const float* bg = (const float*)d_in[2];
  const float* W1 = (const float*)d_in[3];
  const float* b1 = (const float*)d_in[4];
  const float* W2 = (const float*)d_in[5];
  const float* b2 = (const float*)d_in[6];
  float* out = (float*)d_out;

  const size_t SZ_XB  = (size_t)NTOK * DIM * 2;
  const size_t SZ_W1T = (size_t)NEXP * DIM * HDIM * 2;
  const size_t SZ_W2T = (size_t)NEXP * HDIM * DIM * 2;
  const size_t SZ_H1  = (size_t)NTOK * HDIM * 2;
  const size_t SZ_TAIL = (size_t)2 * NTOK * 4 + (size_t)2 * NTOK * 4
                       + (size_t)NTOK * 4 + (size_t)NTOK * 8 + 256
                       + (size_t)2 * MAXTILES * 16 + 1024;
  const size_t NEED_COMB = SZ_XB + SZ_W1T + SZ_W2T + 2 * SZ_H1 + SZ_TAIL;
  int combined = (ws_size >= NEED_COMB) ? 1 : 0;
  size_t szh = combined ? 2 * SZ_H1 : SZ_H1;

  char* ws = (char*)d_ws;
  const size_t OFF_XB  = 0;
  const size_t OFF_W1T = OFF_XB  + SZ_XB;
  const size_t OFF_W2T = OFF_W1T + SZ_W1T;
  const size_t OFF_H   = OFF_W2T + SZ_W2T;
  const size_t OFF_RL  = OFF_H   + szh;
  const size_t OFF_RW  = OFF_RL  + (size_t)2 * NTOK * 4;
  const size_t OFF_E01 = OFF_RW  + (size_t)2 * NTOK * 4;
  const size_t OFF_W01 = OFF_E01 + (size_t)NTOK * 4;
  const size_t OFF_META= OFF_W01 + (size_t)NTOK * 8;
  const size_t OFF_DIR = OFF_META + 256;

  u16*    xb      = (u16*)(ws + OFF_XB);
  u16*    w1t     = (u16*)(ws + OFF_W1T);
  u16*    w2t     = (u16*)(ws + OFF_W2T);
  u16*    h       = (u16*)(ws + OFF_H);
  int*    rowlist = (int*)(ws + OFF_RL);
  float*  roww    = (float*)(ws + OFF_RW);
  int*    e01     = (int*)(ws + OFF_E01);
  float2* w01     = (float2*)(ws + OFF_W01);
  int*    meta    = (int*)(ws + OFF_META);
  int*    counts   = meta;
  int*    offsets  = meta + 16;
  int*    cursors  = meta + 32;
  int*    numTiles = meta + 48;
  int4*   tiledir  = (int4*)(ws + OFF_DIR);

  hipMemsetAsync(meta, 0, 256, stream);
  hipMemsetAsync(out, 0, (size_t)out_size * 4, stream);

  gating_kernel<<<NTOK / 16, 256, 0, stream>>>(x, Wg, bg, e01, w01, counts, xb);
  plan_kernel<<<1, 64, 0, stream>>>(counts, offsets, cursors, numTiles, tiledir, combined);
  scatter_kernel<<<NTOK / 256, 256, 0, stream>>>(e01, w01, cursors, rowlist, roww);

  transpose_convert_kernel<<<dim3(DIM / 64, HDIM / 64, NEXP), 256, 0, stream>>>(W1, w1t, DIM, HDIM);
  transpose_convert_kernel<<<dim3(HDIM / 64, DIM / 64, NEXP), 256, 0, stream>>>(W2, w2t, HDIM, DIM);

  if (combined) {
    gemm1_kernel<<<dim3(GRIDX_COMB, HDIM / BN), 512, GEMM_SMEM, stream>>>(
        xb, w1t, b1, h, rowlist, tiledir, numTiles, 0);
    gemm2_kernel<<<dim3(GRIDX_COMB, DIM / BN), 512, GEMM_SMEM, stream>>>(
        h, w2t, b2, out, rowlist, roww, tiledir, numTiles, 0);
  } else {
    gemm1_kernel<<<dim3(GRIDX_FALL, HDIM / BN), 512, GEMM_SMEM, stream>>>(
        xb, w1t, b1, h, rowlist, tiledir, numTiles, 0);
    gemm2_kernel<<<dim3(GRIDX_FALL, DIM / BN), 512, GEMM_SMEM, stream>>>(
        h, w2t, b2, out, rowlist, roww, tiledir, numTiles, 0);
    gemm1_kernel<<<dim3(GRIDX_FALL, HDIM / BN), 512, GEMM_SMEM, stream>>>(
        xb, w1t, b1, h, rowlist, tiledir + MAXTILES, numTiles + 1, NTOK);
    gemm2_kernel<<<dim3(GRIDX_FALL, DIM / BN), 512, GEMM_SMEM, stream>>>(
        h, w2t, b2, out, rowlist, roww, tiledir + MAXTILES, numTiles + 1, NTOK);
  }
}

// Round 16
// 1118.522 us; speedup vs baseline: 1.0455x; 1.0455x over previous
//
#include <hip/hip_runtime.h>
#include <hip/hip_bf16.h>
#include <cstdint>
#include <cstddef>

#define NTOK 16384
#define DIM 1024
#define NEXP 8
#define HDIM 4096
#define BM 128
#define BN 128
#define BK 64
#define MAXTILES 384
#define GRIDX_COMB 272
#define GRIDX_FALL 144
#define GEMM_SMEM 32768

typedef unsigned short u16;
typedef short bf16x8 __attribute__((ext_vector_type(8)));
typedef float f32x4 __attribute__((ext_vector_type(4)));

typedef const __attribute__((address_space(1))) void* gas_ptr;
typedef __attribute__((address_space(3))) void* las_ptr;

__device__ __forceinline__ void gload16(const void* g, void* l) {
  __builtin_amdgcn_global_load_lds((gas_ptr)g, (las_ptr)l, 16, 0, 0);
}

__device__ __forceinline__ u16 f2b(float f) {
  union { float f; unsigned u; } v;
  v.f = f;
  unsigned r = v.u + 0x7fffu + ((v.u >> 16) & 1u);
  return (u16)(r >> 16);
}

// tanh-form GELU via hw exp/rcp: ~9 branch-free inst, |err| <= ~3e-4 vs exact
__device__ __forceinline__ float gelu_fast(float x) {
  float x2 = x * x;
  float u = x * fmaf(0.044715f, x2, 1.0f);
  float m = fminf(1.5957691216f * u, 55.0f);
  float e = __expf(m);
  float r = __builtin_amdgcn_rcpf(e + 1.0f);
  return x * e * r;
}

// bijective XCD-chunked block swizzle (m204), bx-fastest (R14 proven order)
__device__ __forceinline__ int2 swz_block() {
  int GX = gridDim.x;
  int nwg = GX * (int)gridDim.y;
  int bid = (int)blockIdx.y * GX + (int)blockIdx.x;
  int q = nwg >> 3, r = nwg & 7;
  int xcd = bid & 7, idx = bid >> 3;
  int wg = (xcd < r) ? (xcd * (q + 1) + idx)
                     : (r * (q + 1) + (xcd - r) * q + idx);
  return make_int2(wg % GX, wg / GX);
}

// ---- gating: logits (f64 accum), top-2, softmax weights; also emits xb=bf16(x) ----
__global__ __launch_bounds__(256) void gating_kernel(
    const float* __restrict__ x, const float* __restrict__ Wg,
    const float* __restrict__ bg, int* __restrict__ e01,
    float2* __restrict__ w01, int* __restrict__ counts, u16* __restrict__ xb)
{
  __shared__ float4 wgl[NEXP][256];
  __shared__ int lcnt[16];
  int t = threadIdx.x;
  if (t < 16) lcnt[t] = 0;
  float* wglf = (float*)wgl;
  const float4* wg4 = (const float4*)Wg;
  for (int i = t; i < 2048; i += 256) {
    float4 v = wg4[i];
    int d = i >> 1, eb = (i & 1) * 4;
    wglf[(eb + 0) * 1024 + d] = v.x;
    wglf[(eb + 1) * 1024 + d] = v.y;
    wglf[(eb + 2) * 1024 + d] = v.z;
    wglf[(eb + 3) * 1024 + d] = v.w;
  }
  __syncthreads();
  int lane = t & 63, wid = t >> 6;
  int tok0 = blockIdx.x * 16 + wid * 4;
  for (int s = 0; s < 4; ++s) {
    int n = tok0 + s;
    const float4* xr = (const float4*)(x + (size_t)n * DIM);
    float4 xv[4];
    #pragma unroll
    for (int k = 0; k < 4; ++k) xv[k] = xr[lane + k * 64];
    ushort4* xo = (ushort4*)(xb + (size_t)n * DIM);
    #pragma unroll
    for (int k = 0; k < 4; ++k) {
      ushort4 o;
      o.x = f2b(xv[k].x); o.y = f2b(xv[k].y); o.z = f2b(xv[k].z); o.w = f2b(xv[k].w);
      xo[lane + k * 64] = o;
    }
    double acc[NEXP];
    #pragma unroll
    for (int e = 0; e < NEXP; ++e) acc[e] = 0.0;
    #pragma unroll
    for (int k = 0; k < 4; ++k) {
      #pragma unroll
      for (int e = 0; e < NEXP; ++e) {
        float4 w = wgl[e][lane + k * 64];
        acc[e] += (double)(xv[k].x * w.x) + (double)(xv[k].y * w.y)
                + (double)(xv[k].z * w.z) + (double)(xv[k].w * w.w);
      }
    }
    #pragma unroll
    for (int e = 0; e < NEXP; ++e) {
      for (int off = 32; off; off >>= 1) acc[e] += __shfl_down(acc[e], off, 64);
    }
    if (lane == 0) {
      float v[NEXP];
      #pragma unroll
      for (int e = 0; e < NEXP; ++e) v[e] = (float)acc[e] + bg[e];
      int e0 = 0; float v0 = v[0];
      #pragma unroll
      for (int e = 1; e < NEXP; ++e) if (v[e] > v0) { v0 = v[e]; e0 = e; }
      int e1 = -1; float v1 = -1e30f;
      #pragma unroll
      for (int e = 0; e < NEXP; ++e) if (e != e0 && v[e] > v1) { v1 = v[e]; e1 = e; }
      float d = expf(v1 - v0);
      float w0 = 1.0f / (1.0f + d);
      float w1 = d * w0;
      e01[n] = e0 | (e1 << 8);
      w01[n] = make_float2(w0, w1);
      atomicAdd(&lcnt[e0], 1);
      atomicAdd(&lcnt[8 + e1], 1);
    }
  }
  __syncthreads();
  if (t < 16 && lcnt[t]) atomicAdd(&counts[t], lcnt[t]);
}

// ---------------- plan: offsets + tile directory (128-row tiles) ----------------
__global__ void plan_kernel(const int* __restrict__ counts, int* __restrict__ offsets,
                            int* __restrict__ cursors, int* __restrict__ numTiles,
                            int4* __restrict__ tiledir, int combined)
{
  if (threadIdx.x == 0 && blockIdx.x == 0) {
    for (int p = 0; p < 2; ++p) {
      int o = 0;
      for (int e = 0; e < NEXP; ++e) {
        offsets[p * 8 + e] = o;
        cursors[p * 8 + e] = o;
        o += counts[p * 8 + e];
      }
    }
    if (combined) {
      int idx = 0;
      for (int s = 0; s < 16; ++s) {
        int p = s >> 3, e = s & 7;
        int c = counts[s];
        int base = p * NTOK + offsets[s];
        for (int st = 0; st < c; st += BM) {
          tiledir[idx] = make_int4(e, base + st, (c - st) < BM ? (c - st) : BM, 0);
          ++idx;
        }
      }
      numTiles[0] = idx;
      numTiles[1] = 0;
    } else {
      for (int p = 0; p < 2; ++p) {
        int idx = 0;
        for (int e = 0; e < NEXP; ++e) {
          int c = counts[p * 8 + e];
          int base = p * NTOK + offsets[p * 8 + e];
          for (int st = 0; st < c; st += BM) {
            tiledir[p * MAXTILES + idx] = make_int4(e, base + st, (c - st) < BM ? (c - st) : BM, 0);
            ++idx;
          }
        }
        numTiles[p] = idx;
      }
    }
  }
}

// ---------------- scatter tokens into per-expert lists ----------------
__global__ __launch_bounds__(256) void scatter_kernel(
    const int* __restrict__ e01, const float2* __restrict__ w01,
    int* __restrict__ cursors, int* __restrict__ rowlist, float* __restrict__ roww)
{
  int n = blockIdx.x * 256 + threadIdx.x;
  int ee = e01[n];
  float2 w = w01[n];
  int e0 = ee & 255, e1 = ee >> 8;
  int p0 = atomicAdd(&cursors[e0], 1);
  rowlist[p0] = n; roww[p0] = w.x;
  int p1 = atomicAdd(&cursors[8 + e1], 1);
  rowlist[NTOK + p1] = n; roww[NTOK + p1] = w.y;
}

// ---------------- fp32 [R][C] -> bf16 [C][R] transpose-convert, per expert ----------------
__global__ __launch_bounds__(256) void transpose_convert_kernel(
    const float* __restrict__ in, u16* __restrict__ out, int R, int C)
{
  __shared__ float tile[64][65];
  size_t base = (size_t)blockIdx.z * R * C;
  int r0 = blockIdx.x * 64, c0 = blockIdx.y * 64;
  int t = threadIdx.x;
  int lr = t >> 4, lc4 = (t & 15) * 4;
  #pragma unroll
  for (int i = 0; i < 4; ++i) {
    float4 v = *reinterpret_cast<const float4*>(
        &in[base + (size_t)(r0 + i * 16 + lr) * C + c0 + lc4]);
    tile[i * 16 + lr][lc4 + 0] = v.x;
    tile[i * 16 + lr][lc4 + 1] = v.y;
    tile[i * 16 + lr][lc4 + 2] = v.z;
    tile[i * 16 + lr][lc4 + 3] = v.w;
  }
  __syncthreads();
  #pragma unroll
  for (int i = 0; i < 4; ++i) {
    int oc = i * 16 + lr;
    ushort4 o;
    o.x = f2b(tile[lc4 + 0][oc]);
    o.y = f2b(tile[lc4 + 1][oc]);
    o.z = f2b(tile[lc4 + 2][oc]);
    o.w = f2b(tile[lc4 + 3][oc]);
    *reinterpret_cast<ushort4*>(&out[base + (size_t)(c0 + oc) * R + r0 + lc4]) = o;
  }
}

// ============ m97-structure 128x128 GEMMs: 256 thr, 4 waves (2x2), 32KB single-buf ============
// Per K-step: stage 8 gload16 -> sync -> 16 ds_read_b128 + 32 MFMA -> sync. 3+ blocks/CU.
// LDS chunk swizzle: phys chunk q (row=q>>3,pos8=q&7) holds logical chunk pos8^(row&7).

// GEMM1: h[row - hbase] = gelu_fast(gather(x) @ W1[e]' + b1[e])
__global__ __launch_bounds__(256, 3) void gemm1_kernel(
    const u16* __restrict__ xb, const u16* __restrict__ w1t,
    const float* __restrict__ b1, u16* __restrict__ h,
    const int* __restrict__ rowlist, const int4* __restrict__ tiledir,
    const int* __restrict__ numTiles, int hbase)
{
  extern __shared__ u16 smem[];         // A: 8192 u16 | B: 8192 u16
  __shared__ int tok[BM];
  int2 bxy = swz_block();
  int bx = bxy.x, by = bxy.y;
  if (bx >= *numTiles) return;
  int4 td = tiledir[bx];
  int e = td.x, row0 = td.y, rows = td.z;
  int n0 = by * BN;
  int t = threadIdx.x, lane = t & 63, wid = t >> 6;
  for (int i = t; i < BM; i += 256) {
    int p = row0 + i; if (p > 2 * NTOK - 1) p = 2 * NTOK - 1;
    tok[i] = rowlist[p];
  }
  __syncthreads();
  // staging: thread covers chunks q = t + i*256, i=0..3 over 1024 chunks (A), same for B
  int qoff[4]; const u16* gA[4]; const u16* gB[4];
  #pragma unroll
  for (int i = 0; i < 4; ++i) {
    int q = t + i * 256;
    int row = q >> 3, c = (q & 7) ^ (row & 7);
    qoff[i] = q * 8;
    gA[i] = xb + (size_t)tok[row] * DIM + c * 8;
    gB[i] = w1t + ((size_t)e * HDIM + n0 + row) * DIM + c * 8;
  }
  f32x4 acc[4][4] = {};
  int wr = wid >> 1, wc = wid & 1;
  int arow = lane & 15, cbase = lane >> 4, csw = arow & 7;
  const int NKT = DIM / BK;   // 16
  for (int kt = 0; kt < NKT; ++kt) {
    #pragma unroll
    for (int i = 0; i < 4; ++i) {
      gload16(gA[i] + kt * BK, &smem[qoff[i]]);
      gload16(gB[i] + kt * BK, &smem[8192 + qoff[i]]);
    }
    __syncthreads();
    #pragma unroll
    for (int kk = 0; kk < 2; ++kk) {
      int cp = ((kk * 4 + cbase) ^ csw) * 8;
      bf16x8 a[4], b[4];
      #pragma unroll
      for (int m = 0; m < 4; ++m)
        a[m] = *reinterpret_cast<const bf16x8*>(&smem[(wr * 64 + m * 16 + arow) * 64 + cp]);
      #pragma unroll
      for (int n = 0; n < 4; ++n)
        b[n] = *reinterpret_cast<const bf16x8*>(&smem[8192 + (wc * 64 + n * 16 + arow) * 64 + cp]);
      __builtin_amdgcn_s_setprio(1);
      #pragma unroll
      for (int m = 0; m < 4; ++m)
        #pragma unroll
        for (int n = 0; n < 4; ++n)
          acc[m][n] = __builtin_amdgcn_mfma_f32_16x16x32_bf16(a[m], b[n], acc[m][n], 0, 0, 0);
      __builtin_amdgcn_s_setprio(0);
    }
    __syncthreads();
  }
  int rsub = (lane >> 4) * 4;
  #pragma unroll
  for (int m = 0; m < 4; ++m) {
    int lrb = wr * 64 + m * 16 + rsub;
    #pragma unroll
    for (int n = 0; n < 4; ++n) {
      int col = n0 + wc * 64 + n * 16 + arow;
      float bv = b1[e * HDIM + col];
      #pragma unroll
      for (int r = 0; r < 4; ++r) {
        int lr = lrb + r;
        if (lr < rows) {
          float v = gelu_fast(acc[m][n][r] + bv);
          h[(size_t)(row0 + lr - hbase) * HDIM + col] = f2b(v);
        }
      }
    }
  }
}

// GEMM2: out[tok] += w * (h[row - hbase] @ W2[e]' + b2[e])   (atomicAdd, out pre-zeroed)
__global__ __launch_bounds__(256, 3) void gemm2_kernel(
    const u16* __restrict__ h, const u16* __restrict__ w2t,
    const float* __restrict__ b2, float* __restrict__ out,
    const int* __restrict__ rowlist, const float* __restrict__ roww,
    const int4* __restrict__ tiledir, const int* __restrict__ numTiles, int hbase)
{
  extern __shared__ u16 smem[];
  __shared__ int tok[BM];
  __shared__ float wt[BM];
  int2 bxy = swz_block();
  int bx = bxy.x, by = bxy.y;
  if (bx >= *numTiles) return;
  int4 td = tiledir[bx];
  int e = td.x, row0 = td.y, rows = td.z;
  int n0 = by * BN;
  int t = threadIdx.x, lane = t & 63, wid = t >> 6;
  for (int i = t; i < BM; i += 256) {
    int p = row0 + i; if (p > 2 * NTOK - 1) p = 2 * NTOK - 1;
    tok[i] = rowlist[p];
    wt[i] = roww[p];
  }
  __syncthreads();
  int qoff[4]; const u16* gA[4]; const u16* gB[4];
  #pragma unroll
  for (int i = 0; i < 4; ++i) {
    int q = t + i * 256;
    int row = q >> 3, c = (q & 7) ^ (row & 7);
    qoff[i] = q * 8;
    int hr = row < rows ? row : (rows - 1);
    gA[i] = h + (size_t)(row0 + hr - hbase) * HDIM + c * 8;
    gB[i] = w2t + ((size_t)e * DIM + n0 + row) * HDIM + c * 8;
  }
  f32x4 acc[4][4] = {};
  int wr = wid >> 1, wc = wid & 1;
  int arow = lane & 15, cbase = lane >> 4, csw = arow & 7;
  const int NKT = HDIM / BK;   // 64
  for (int kt = 0; kt < NKT; ++kt) {
    #pragma unroll
    for (int i = 0; i < 4; ++i) {
      gload16(gA[i] + kt * BK, &smem[qoff[i]]);
      gload16(gB[i] + kt * BK, &smem[8192 + qoff[i]]);
    }
    __syncthreads();
    #pragma unroll
    for (int kk = 0; kk < 2; ++kk) {
      int cp = ((kk * 4 + cbase) ^ csw) * 8;
      bf16x8 a[4], b[4];
      #pragma unroll
      for (int m = 0; m < 4; ++m)
        a[m] = *reinterpret_cast<const bf16x8*>(&smem[(wr * 64 + m * 16 + arow) * 64 + cp]);
      #pragma unroll
      for (int n = 0; n < 4; ++n)
        b[n] = *reinterpret_cast<const bf16x8*>(&smem[8192 + (wc * 64 + n * 16 + arow) * 64 + cp]);
      __builtin_amdgcn_s_setprio(1);
      #pragma unroll
      for (int m = 0; m < 4; ++m)
        #pragma unroll
        for (int n = 0; n < 4; ++n)
          acc[m][n] = __builtin_amdgcn_mfma_f32_16x16x32_bf16(a[m], b[n], acc[m][n], 0, 0, 0);
      __builtin_amdgcn_s_setprio(0);
    }
    __syncthreads();
  }
  int rsub = (lane >> 4) * 4;
  #pragma unroll
  for (int m = 0; m < 4; ++m) {
    int lrb = wr * 64 + m * 16 + rsub;
    #pragma unroll
    for (int n = 0; n < 4; ++n) {
      int col = n0 + wc * 64 + n * 16 + arow;
      float bv = b2[e * DIM + col];
      #pragma unroll
      for (int r = 0; r < 4; ++r) {
        int lr = lrb + r;
        if (lr < rows) {
          float v = (acc[m][n][r] + bv) * wt[lr];
          atomicAdd(&out[(size_t)tok[lr] * DIM + col], v);
        }
      }
    }
  }
}

// ---------------- launcher ----------------
extern "C" void kernel_launch(void* const* d_in, const int* in_sizes, int n_in,
                              void* d_out, int out_size, void* d_ws, size_t ws_size,
                              hipStream_t stream)
{
  const float* x  = (const float*)d_in[0];
  const float* Wg = (const float*)d_in[1];
  const float* bg = (const float*)d_in[2];
  const float* W1 = (const float*)d_in[3];
  const float* b1 = (const float*)d_in[4];
  const float* W2 = (const float*)d_in[5];
  const float* b2 = (const float*)d_in[6];
  float* out = (float*)d_out;

  const size_t SZ_XB  = (size_t)NTOK * DIM * 2;
  const size_t SZ_W1T = (size_t)NEXP * DIM * HDIM * 2;
  const size_t SZ_W2T = (size_t)NEXP * HDIM * DIM * 2;
  const size_t SZ_H1  = (size_t)NTOK * HDIM * 2;
  const size_t SZ_TAIL = (size_t)2 * NTOK * 4 + (size_t)2 * NTOK * 4
                       + (size_t)NTOK * 4 + (size_t)NTOK * 8 + 256
                       + (size_t)2 * MAXTILES * 16 + 1024;
  const size_t NEED_COMB = SZ_XB + SZ_W1T + SZ_W2T + 2 * SZ_H1 + SZ_TAIL;
  int combined = (ws_size >= NEED_COMB) ? 1 : 0;
  size_t szh = combined ? 2 * SZ_H1 : SZ_H1;

  char* ws = (char*)d_ws;
  const size_t OFF_XB  = 0;
  const size_t OFF_W1T = OFF_XB  + SZ_XB;
  const size_t OFF_W2T = OFF_W1T + SZ_W1T;
  const size_t OFF_H   = OFF_W2T + SZ_W2T;
  const size_t OFF_RL  = OFF_H   + szh;
  const size_t OFF_RW  = OFF_RL  + (size_t)2 * NTOK * 4;
  const size_t OFF_E01 = OFF_RW  + (size_t)2 * NTOK * 4;
  const size_t OFF_W01 = OFF_E01 + (size_t)NTOK * 4;
  const size_t OFF_META= OFF_W01 + (size_t)NTOK * 8;
  const size_t OFF_DIR = OFF_META + 256;

  u16*    xb      = (u16*)(ws + OFF_XB);
  u16*    w1t     = (u16*)(ws + OFF_W1T);
  u16*    w2t     = (u16*)(ws + OFF_W2T);
  u16*    h       = (u16*)(ws + OFF_H);
  int*    rowlist = (int*)(ws + OFF_RL);
  float*  roww    = (float*)(ws + OFF_RW);
  int*    e01     = (int*)(ws + OFF_E01);
  float2* w01     = (float2*)(ws + OFF_W01);
  int*    meta    = (int*)(ws + OFF_META);
  int*    counts   = meta;
  int*    offsets  = meta + 16;
  int*    cursors  = meta + 32;
  int*    numTiles = meta + 48;
  int4*   tiledir  = (int4*)(ws + OFF_DIR);

  hipMemsetAsync(meta, 0, 256, stream);
  hipMemsetAsync(out, 0, (size_t)out_size * 4, stream);

  gating_kernel<<<NTOK / 16, 256, 0, stream>>>(x, Wg, bg, e01, w01, counts, xb);
  plan_kernel<<<1, 64, 0, stream>>>(counts, offsets, cursors, numTiles, tiledir, combined);
  scatter_kernel<<<NTOK / 256, 256, 0, stream>>>(e01, w01, cursors, rowlist, roww);

  transpose_convert_kernel<<<dim3(DIM / 64, HDIM / 64, NEXP), 256, 0, stream>>>(W1, w1t, DIM, HDIM);
  transpose_convert_kernel<<<dim3(HDIM / 64, DIM / 64, NEXP), 256, 0, stream>>>(W2, w2t, HDIM, DIM);

  if (combined) {
    gemm1_kernel<<<dim3(GRIDX_COMB, HDIM / BN), 256, GEMM_SMEM, stream>>>(
        xb, w1t, b1, h, rowlist, tiledir, numTiles, 0);
    gemm2_kernel<<<dim3(GRIDX_COMB, DIM / BN), 256, GEMM_SMEM, stream>>>(
        h, w2t, b2, out, rowlist, roww, tiledir, numTiles, 0);
  } else {
    gemm1_kernel<<<dim3(GRIDX_FALL, HDIM / BN), 256, GEMM_SMEM, stream>>>(
        xb, w1t, b1, h, rowlist, tiledir, numTiles, 0);
    gemm2_kernel<<<dim3(GRIDX_FALL, DIM / BN), 256, GEMM_SMEM, stream>>>(
        h, w2t, b2, out, rowlist, roww, tiledir, numTiles, 0);
    gemm1_kernel<<<dim3(GRIDX_FALL, HDIM / BN), 256, GEMM_SMEM, stream>>>(
        xb, w1t, b1, h, rowlist, tiledir + MAXTILES, numTiles + 1, NTOK);
    gemm2_kernel<<<dim3(GRIDX_FALL, DIM / BN), 256, GEMM_SMEM, stream>>>(
        h, w2t, b2, out, rowlist, roww, tiledir + MAXTILES, numTiles + 1, NTOK);
  }
}

// Round 17
// 1004.856 us; speedup vs baseline: 1.1637x; 1.1131x over previous
//
#include <hip/hip_runtime.h>
#include <hip/hip_bf16.h>
#include <cstdint>
#include <cstddef>

#define NTOK 16384
#define DIM 1024
#define NEXP 8
#define HDIM 4096
#define BM 128
#define BN 128
#define BK 64
#define MAXTILES 384
#define GRIDX_COMB 272
#define GRIDX_FALL 144
#define GEMM_SMEM 32768

typedef unsigned short u16;
typedef short bf16x8 __attribute__((ext_vector_type(8)));
typedef float f32x4 __attribute__((ext_vector_type(4)));

typedef const __attribute__((address_space(1))) void* gas_ptr;
typedef __attribute__((address_space(3))) void* las_ptr;

__device__ __forceinline__ void gload16(const void* g, void* l) {
  __builtin_amdgcn_global_load_lds((gas_ptr)g, (las_ptr)l, 16, 0, 0);
}

__device__ __forceinline__ u16 f2b(float f) {
  union { float f; unsigned u; } v;
  v.f = f;
  unsigned r = v.u + 0x7fffu + ((v.u >> 16) & 1u);
  return (u16)(r >> 16);
}

// tanh-form GELU via hw exp/rcp: ~9 branch-free inst, |err| <= ~3e-4 vs exact
__device__ __forceinline__ float gelu_fast(float x) {
  float x2 = x * x;
  float u = x * fmaf(0.044715f, x2, 1.0f);
  float m = fminf(1.5957691216f * u, 55.0f);
  float e = __expf(m);
  float r = __builtin_amdgcn_rcpf(e + 1.0f);
  return x * e * r;
}

// bijective XCD-chunked swizzle (m204) + 4-panel grouping:
// consecutive same-XCD blocks cover the 4 panels of ONE row-tile -> A-tile L2 reuse x4,
// then advance tile (B stays L2/L3-shared). GY must be a multiple of 4.
__device__ __forceinline__ int2 swz_group4() {
  int GX = gridDim.x, GY = gridDim.y;
  int nwg = GX * GY;
  int bid = (int)blockIdx.y * GX + (int)blockIdx.x;
  int q = nwg >> 3, r = nwg & 7;
  int xcd = bid & 7, idx = bid >> 3;
  int wg = (xcd < r) ? (xcd * (q + 1) + idx)
                     : (r * (q + 1) + (xcd - r) * q + idx);
  int span = GX << 2;                 // GX * 4
  int pg = wg / span, rem = wg % span;
  int tile = rem >> 2, pl = rem & 3;
  return make_int2(tile, (pg << 2) + pl);
}

// ---- gating: logits (f64 accum), top-2, softmax weights; also emits xb=bf16(x) ----
__global__ __launch_bounds__(256) void gating_kernel(
    const float* __restrict__ x, const float* __restrict__ Wg,
    const float* __restrict__ bg, int* __restrict__ e01,
    float2* __restrict__ w01, int* __restrict__ counts, u16* __restrict__ xb)
{
  __shared__ float4 wgl[NEXP][256];
  __shared__ int lcnt[16];
  int t = threadIdx.x;
  if (t < 16) lcnt[t] = 0;
  float* wglf = (float*)wgl;
  const float4* wg4 = (const float4*)Wg;
  for (int i = t; i < 2048; i += 256) {
    float4 v = wg4[i];
    int d = i >> 1, eb = (i & 1) * 4;
    wglf[(eb + 0) * 1024 + d] = v.x;
    wglf[(eb + 1) * 1024 + d] = v.y;
    wglf[(eb + 2) * 1024 + d] = v.z;
    wglf[(eb + 3) * 1024 + d] = v.w;
  }
  __syncthreads();
  int lane = t & 63, wid = t >> 6;
  int tok0 = blockIdx.x * 16 + wid * 4;
  for (int s = 0; s < 4; ++s) {
    int n = tok0 + s;
    const float4* xr = (const float4*)(x + (size_t)n * DIM);
    float4 xv[4];
    #pragma unroll
    for (int k = 0; k < 4; ++k) xv[k] = xr[lane + k * 64];
    ushort4* xo = (ushort4*)(xb + (size_t)n * DIM);
    #pragma unroll
    for (int k = 0; k < 4; ++k) {
      ushort4 o;
      o.x = f2b(xv[k].x); o.y = f2b(xv[k].y); o.z = f2b(xv[k].z); o.w = f2b(xv[k].w);
      xo[lane + k * 64] = o;
    }
    double acc[NEXP];
    #pragma unroll
    for (int e = 0; e < NEXP; ++e) acc[e] = 0.0;
    #pragma unroll
    for (int k = 0; k < 4; ++k) {
      #pragma unroll
      for (int e = 0; e < NEXP; ++e) {
        float4 w = wgl[e][lane + k * 64];
        acc[e] += (double)(xv[k].x * w.x) + (double)(xv[k].y * w.y)
                + (double)(xv[k].z * w.z) + (double)(xv[k].w * w.w);
      }
    }
    #pragma unroll
    for (int e = 0; e < NEXP; ++e) {
      for (int off = 32; off; off >>= 1) acc[e] += __shfl_down(acc[e], off, 64);
    }
    if (lane == 0) {
      float v[NEXP];
      #pragma unroll
      for (int e = 0; e < NEXP; ++e) v[e] = (float)acc[e] + bg[e];
      int e0 = 0; float v0 = v[0];
      #pragma unroll
      for (int e = 1; e < NEXP; ++e) if (v[e] > v0) { v0 = v[e]; e0 = e; }
      int e1 = -1; float v1 = -1e30f;
      #pragma unroll
      for (int e = 0; e < NEXP; ++e) if (e != e0 && v[e] > v1) { v1 = v[e]; e1 = e; }
      float d = expf(v1 - v0);
      float w0 = 1.0f / (1.0f + d);
      float w1 = d * w0;
      e01[n] = e0 | (e1 << 8);
      w01[n] = make_float2(w0, w1);
      atomicAdd(&lcnt[e0], 1);
      atomicAdd(&lcnt[8 + e1], 1);
    }
  }
  __syncthreads();
  if (t < 16 && lcnt[t]) atomicAdd(&counts[t], lcnt[t]);
}

// ---------------- plan: offsets + tile directory (128-row tiles) ----------------
__global__ void plan_kernel(const int* __restrict__ counts, int* __restrict__ offsets,
                            int* __restrict__ cursors, int* __restrict__ numTiles,
                            int4* __restrict__ tiledir, int combined)
{
  if (threadIdx.x == 0 && blockIdx.x == 0) {
    for (int p = 0; p < 2; ++p) {
      int o = 0;
      for (int e = 0; e < NEXP; ++e) {
        offsets[p * 8 + e] = o;
        cursors[p * 8 + e] = o;
        o += counts[p * 8 + e];
      }
    }
    if (combined) {
      int idx = 0;
      for (int s = 0; s < 16; ++s) {
        int p = s >> 3, e = s & 7;
        int c = counts[s];
        int base = p * NTOK + offsets[s];
        for (int st = 0; st < c; st += BM) {
          tiledir[idx] = make_int4(e, base + st, (c - st) < BM ? (c - st) : BM, 0);
          ++idx;
        }
      }
      numTiles[0] = idx;
      numTiles[1] = 0;
    } else {
      for (int p = 0; p < 2; ++p) {
        int idx = 0;
        for (int e = 0; e < NEXP; ++e) {
          int c = counts[p * 8 + e];
          int base = p * NTOK + offsets[p * 8 + e];
          for (int st = 0; st < c; st += BM) {
            tiledir[p * MAXTILES + idx] = make_int4(e, base + st, (c - st) < BM ? (c - st) : BM, 0);
            ++idx;
          }
        }
        numTiles[p] = idx;
      }
    }
  }
}

// ---------------- scatter tokens into per-expert lists ----------------
__global__ __launch_bounds__(256) void scatter_kernel(
    const int* __restrict__ e01, const float2* __restrict__ w01,
    int* __restrict__ cursors, int* __restrict__ rowlist, float* __restrict__ roww)
{
  int n = blockIdx.x * 256 + threadIdx.x;
  int ee = e01[n];
  float2 w = w01[n];
  int e0 = ee & 255, e1 = ee >> 8;
  int p0 = atomicAdd(&cursors[e0], 1);
  rowlist[p0] = n; roww[p0] = w.x;
  int p1 = atomicAdd(&cursors[8 + e1], 1);
  rowlist[NTOK + p1] = n; roww[NTOK + p1] = w.y;
}

// ---------------- fp32 [R][C] -> bf16 [C][R] transpose-convert, per expert ----------------
__global__ __launch_bounds__(256) void transpose_convert_kernel(
    const float* __restrict__ in, u16* __restrict__ out, int R, int C)
{
  __shared__ float tile[64][65];
  size_t base = (size_t)blockIdx.z * R * C;
  int r0 = blockIdx.x * 64, c0 = blockIdx.y * 64;
  int t = threadIdx.x;
  int lr = t >> 4, lc4 = (t & 15) * 4;
  #pragma unroll
  for (int i = 0; i < 4; ++i) {
    float4 v = *reinterpret_cast<const float4*>(
        &in[base + (size_t)(r0 + i * 16 + lr) * C + c0 + lc4]);
    tile[i * 16 + lr][lc4 + 0] = v.x;
    tile[i * 16 + lr][lc4 + 1] = v.y;
    tile[i * 16 + lr][lc4 + 2] = v.z;
    tile[i * 16 + lr][lc4 + 3] = v.w;
  }
  __syncthreads();
  #pragma unroll
  for (int i = 0; i < 4; ++i) {
    int oc = i * 16 + lr;
    ushort4 o;
    o.x = f2b(tile[lc4 + 0][oc]);
    o.y = f2b(tile[lc4 + 1][oc]);
    o.z = f2b(tile[lc4 + 2][oc]);
    o.w = f2b(tile[lc4 + 3][oc]);
    *reinterpret_cast<ushort4*>(&out[base + (size_t)(c0 + oc) * R + r0 + lc4]) = o;
  }
}

// ============ m97-structure 128x128 GEMMs: 256 thr, 4 waves (2x2), 32KB single-buf ============
// Per K-step: stage 8 gload16 -> sync -> 16 ds_read_b128 + 32 MFMA -> sync. 3+ blocks/CU.
// LDS chunk swizzle: phys chunk q (row=q>>3,pos8=q&7) holds logical chunk pos8^(row&7).
// Block order: 4-panel groups (A-tile L2 reuse x4).

// GEMM1: h[row - hbase] = gelu_fast(gather(x) @ W1[e]' + b1[e])
__global__ __launch_bounds__(256, 3) void gemm1_kernel(
    const u16* __restrict__ xb, const u16* __restrict__ w1t,
    const float* __restrict__ b1, u16* __restrict__ h,
    const int* __restrict__ rowlist, const int4* __restrict__ tiledir,
    const int* __restrict__ numTiles, int hbase)
{
  extern __shared__ u16 smem[];         // A: 8192 u16 | B: 8192 u16
  __shared__ int tok[BM];
  int2 bxy = swz_group4();
  int bx = bxy.x, by = bxy.y;
  if (bx >= *numTiles) return;
  int4 td = tiledir[bx];
  int e = td.x, row0 = td.y, rows = td.z;
  int n0 = by * BN;
  int t = threadIdx.x, lane = t & 63, wid = t >> 6;
  for (int i = t; i < BM; i += 256) {
    int p = row0 + i; if (p > 2 * NTOK - 1) p = 2 * NTOK - 1;
    tok[i] = rowlist[p];
  }
  __syncthreads();
  // staging: thread covers chunks q = t + i*256, i=0..3 over 1024 chunks (A), same for B
  int qoff[4]; const u16* gA[4]; const u16* gB[4];
  #pragma unroll
  for (int i = 0; i < 4; ++i) {
    int q = t + i * 256;
    int row = q >> 3, c = (q & 7) ^ (row & 7);
    qoff[i] = q * 8;
    gA[i] = xb + (size_t)tok[row] * DIM + c * 8;
    gB[i] = w1t + ((size_t)e * HDIM + n0 + row) * DIM + c * 8;
  }
  f32x4 acc[4][4] = {};
  int wr = wid >> 1, wc = wid & 1;
  int arow = lane & 15, cbase = lane >> 4, csw = arow & 7;
  const int NKT = DIM / BK;   // 16
  for (int kt = 0; kt < NKT; ++kt) {
    #pragma unroll
    for (int i = 0; i < 4; ++i) {
      gload16(gA[i] + kt * BK, &smem[qoff[i]]);
      gload16(gB[i] + kt * BK, &smem[8192 + qoff[i]]);
    }
    __syncthreads();
    #pragma unroll
    for (int kk = 0; kk < 2; ++kk) {
      int cp = ((kk * 4 + cbase) ^ csw) * 8;
      bf16x8 a[4], b[4];
      #pragma unroll
      for (int m = 0; m < 4; ++m)
        a[m] = *reinterpret_cast<const bf16x8*>(&smem[(wr * 64 + m * 16 + arow) * 64 + cp]);
      #pragma unroll
      for (int n = 0; n < 4; ++n)
        b[n] = *reinterpret_cast<const bf16x8*>(&smem[8192 + (wc * 64 + n * 16 + arow) * 64 + cp]);
      __builtin_amdgcn_s_setprio(1);
      #pragma unroll
      for (int m = 0; m < 4; ++m)
        #pragma unroll
        for (int n = 0; n < 4; ++n)
          acc[m][n] = __builtin_amdgcn_mfma_f32_16x16x32_bf16(a[m], b[n], acc[m][n], 0, 0, 0);
      __builtin_amdgcn_s_setprio(0);
    }
    __syncthreads();
  }
  int rsub = (lane >> 4) * 4;
  #pragma unroll
  for (int m = 0; m < 4; ++m) {
    int lrb = wr * 64 + m * 16 + rsub;
    #pragma unroll
    for (int n = 0; n < 4; ++n) {
      int col = n0 + wc * 64 + n * 16 + arow;
      float bv = b1[e * HDIM + col];
      #pragma unroll
      for (int r = 0; r < 4; ++r) {
        int lr = lrb + r;
        if (lr < rows) {
          float v = gelu_fast(acc[m][n][r] + bv);
          h[(size_t)(row0 + lr - hbase) * HDIM + col] = f2b(v);
        }
      }
    }
  }
}

// GEMM2: out[tok] += w * (h[row - hbase] @ W2[e]' + b2[e])   (atomicAdd, out pre-zeroed)
__global__ __launch_bounds__(256, 3) void gemm2_kernel(
    const u16* __restrict__ h, const u16* __restrict__ w2t,
    const float* __restrict__ b2, float* __restrict__ out,
    const int* __restrict__ rowlist, const float* __restrict__ roww,
    const int4* __restrict__ tiledir, const int* __restrict__ numTiles, int hbase)
{
  extern __shared__ u16 smem[];
  __shared__ int tok[BM];
  __shared__ float wt[BM];
  int2 bxy = swz_group4();
  int bx = bxy.x, by = bxy.y;
  if (bx >= *numTiles) return;
  int4 td = tiledir[bx];
  int e = td.x, row0 = td.y, rows = td.z;
  int n0 = by * BN;
  int t = threadIdx.x, lane = t & 63, wid = t >> 6;
  for (int i = t; i < BM; i += 256) {
    int p = row0 + i; if (p > 2 * NTOK - 1) p = 2 * NTOK - 1;
    tok[i] = rowlist[p];
    wt[i] = roww[p];
  }
  __syncthreads();
  int qoff[4]; const u16* gA[4]; const u16* gB[4];
  #pragma unroll
  for (int i = 0; i < 4; ++i) {
    int q = t + i * 256;
    int row = q >> 3, c = (q & 7) ^ (row & 7);
    qoff[i] = q * 8;
    int hr = row < rows ? row : (rows - 1);
    gA[i] = h + (size_t)(row0 + hr - hbase) * HDIM + c * 8;
    gB[i] = w2t + ((size_t)e * DIM + n0 + row) * HDIM + c * 8;
  }
  f32x4 acc[4][4] = {};
  int wr = wid >> 1, wc = wid & 1;
  int arow = lane & 15, cbase = lane >> 4, csw = arow & 7;
  const int NKT = HDIM / BK;   // 64
  for (int kt = 0; kt < NKT; ++kt) {
    #pragma unroll
    for (int i = 0; i < 4; ++i) {
      gload16(gA[i] + kt * BK, &smem[qoff[i]]);
      gload16(gB[i] + kt * BK, &smem[8192 + qoff[i]]);
    }
    __syncthreads();
    #pragma unroll
    for (int kk = 0; kk < 2; ++kk) {
      int cp = ((kk * 4 + cbase) ^ csw) * 8;
      bf16x8 a[4], b[4];
      #pragma unroll
      for (int m = 0; m < 4; ++m)
        a[m] = *reinterpret_cast<const bf16x8*>(&smem[(wr * 64 + m * 16 + arow) * 64 + cp]);
      #pragma unroll
      for (int n = 0; n < 4; ++n)
        b[n] = *reinterpret_cast<const bf16x8*>(&smem[8192 + (wc * 64 + n * 16 + arow) * 64 + cp]);
      __builtin_amdgcn_s_setprio(1);
      #pragma unroll
      for (int m = 0; m < 4; ++m)
        #pragma unroll
        for (int n = 0; n < 4; ++n)
          acc[m][n] = __builtin_amdgcn_mfma_f32_16x16x32_bf16(a[m], b[n], acc[m][n], 0, 0, 0);
      __builtin_amdgcn_s_setprio(0);
    }
    __syncthreads();
  }
  int rsub = (lane >> 4) * 4;
  #pragma unroll
  for (int m = 0; m < 4; ++m) {
    int lrb = wr * 64 + m * 16 + rsub;
    #pragma unroll
    for (int n = 0; n < 4; ++n) {
      int col = n0 + wc * 64 + n * 16 + arow;
      float bv = b2[e * DIM + col];
      #pragma unroll
      for (int r = 0; r < 4; ++r) {
        int lr = lrb + r;
        if (lr < rows) {
          float v = (acc[m][n][r] + bv) * wt[lr];
          atomicAdd(&out[(size_t)tok[lr] * DIM + col], v);
        }
      }
    }
  }
}

// ---------------- launcher ----------------
extern "C" void kernel_launch(void* const* d_in, const int* in_sizes, int n_in,
                              void* d_out, int out_size, void* d_ws, size_t ws_size,
                              hipStream_t stream)
{
  const float* x  = (const float*)d_in[0];
  const float* Wg = (const float*)d_in[1];
  const float* bg = (const float*)d_in[2];
  const float* W1 = (const float*)d_in[3];
  const float* b1 = (const float*)d_in[4];
  const float* W2 = (const float*)d_in[5];
  const float* b2 = (const float*)d_in[6];
  float* out = (float*)d_out;

  const size_t SZ_XB  = (size_t)NTOK * DIM * 2;
  const size_t SZ_W1T = (size_t)NEXP * DIM * HDIM * 2;
  const size_t SZ_W2T = (size_t)NEXP * HDIM * DIM * 2;
  const size_t SZ_H1  = (size_t)NTOK * HDIM * 2;
  const size_t SZ_TAIL = (size_t)2 * NTOK * 4 + (size_t)2 * NTOK * 4
                       + (size_t)NTOK * 4 + (size_t)NTOK * 8 + 256
                       + (size_t)2 * MAXTILES * 16 + 1024;
  const size_t NEED_COMB = SZ_XB + SZ_W1T + SZ_W2T + 2 * SZ_H1 + SZ_TAIL;
  int combined = (ws_size >= NEED_COMB) ? 1 : 0;
  size_t szh = combined ? 2 * SZ_H1 : SZ_H1;

  char* ws = (char*)d_ws;
  const size_t OFF_XB  = 0;
  const size_t OFF_W1T = OFF_XB  + SZ_XB;
  const size_t OFF_W2T = OFF_W1T + SZ_W1T;
  const size_t OFF_H   = OFF_W2T + SZ_W2T;
  const size_t OFF_RL  = OFF_H   + szh;
  const size_t OFF_RW  = OFF_RL  + (size_t)2 * NTOK * 4;
  const size_t OFF_E01 = OFF_RW  + (size_t)2 * NTOK * 4;
  const size_t OFF_W01 = OFF_E01 + (size_t)NTOK * 4;
  const size_t OFF_META= OFF_W01 + (size_t)NTOK * 8;
  const size_t OFF_DIR = OFF_META + 256;

  u16*    xb      = (u16*)(ws + OFF_XB);
  u16*    w1t     = (u16*)(ws + OFF_W1T);
  u16*    w2t     = (u16*)(ws + OFF_W2T);
  u16*    h       = (u16*)(ws + OFF_H);
  int*    rowlist = (int*)(ws + OFF_RL);
  float*  roww    = (float*)(ws + OFF_RW);
  int*    e01     = (int*)(ws + OFF_E01);
  float2* w01     = (float2*)(ws + OFF_W01);
  int*    meta    = (int*)(ws + OFF_META);
  int*    counts   = meta;
  int*    offsets  = meta + 16;
  int*    cursors  = meta + 32;
  int*    numTiles = meta + 48;
  int4*   tiledir  = (int4*)(ws + OFF_DIR);

  hipMemsetAsync(meta, 0, 256, stream);
  hipMemsetAsync(out, 0, (size_t)out_size * 4, stream);

  gating_kernel<<<NTOK / 16, 256, 0, stream>>>(x, Wg, bg, e01, w01, counts, xb);
  plan_kernel<<<1, 64, 0, stream>>>(counts, offsets, cursors, numTiles, tiledir, combined);
  scatter_kernel<<<NTOK / 256, 256, 0, stream>>>(e01, w01, cursors, rowlist, roww);

  transpose_convert_kernel<<<dim3(DIM / 64, HDIM / 64, NEXP), 256, 0, stream>>>(W1, w1t, DIM, HDIM);
  transpose_convert_kernel<<<dim3(HDIM / 64, DIM / 64, NEXP), 256, 0, stream>>>(W2, w2t, HDIM, DIM);

  if (combined) {
    gemm1_kernel<<<dim3(GRIDX_COMB, HDIM / BN), 256, GEMM_SMEM, stream>>>(
        xb, w1t, b1, h, rowlist, tiledir, numTiles, 0);
    gemm2_kernel<<<dim3(GRIDX_COMB, DIM / BN), 256, GEMM_SMEM, stream>>>(
        h, w2t, b2, out, rowlist, roww, tiledir, numTiles, 0);
  } else {
    gemm1_kernel<<<dim3(GRIDX_FALL, HDIM / BN), 256, GEMM_SMEM, stream>>>(
        xb, w1t, b1, h, rowlist, tiledir, numTiles, 0);
    gemm2_kernel<<<dim3(GRIDX_FALL, DIM / BN), 256, GEMM_SMEM, stream>>>(
        h, w2t, b2, out, rowlist, roww, tiledir, numTiles, 0);
    gemm1_kernel<<<dim3(GRIDX_FALL, HDIM / BN), 256, GEMM_SMEM, stream>>>(
        xb, w1t, b1, h, rowlist, tiledir + MAXTILES, numTiles + 1, NTOK);
    gemm2_kernel<<<dim3(GRIDX_FALL, DIM / BN), 256, GEMM_SMEM, stream>>>(
        h, w2t, b2, out, rowlist, roww, tiledir + MAXTILES, numTiles + 1, NTOK);
  }
}